// Round 1
// baseline (5793.921 us; speedup 1.0000x reference)
//
#include <hip/hip_runtime.h>
#include <hip/hip_bf16.h>
#include <math.h>

// GPT-2 small, 4 layers: V=50257, T=1024, D=768, F=3072, H=12, HD=64, B=2.
// Round 0: all-fp32 correctness-first implementation.
// Workspace layout (fp32): X[2048*768] | H[2048*768] | QKV[2048*2304] | U[2048*3072]
//   = 6.29 + 6.29 + 18.87 + 25.17 MB = 56.6 MB total.

constexpr int kB  = 2;
constexpr int kT  = 1024;
constexpr int kD  = 768;
constexpr int kF  = 3072;
constexpr int kH  = 12;
constexpr int kHD = 64;
constexpr int kL  = 4;
constexpr int kV  = 50257;
constexpr int kM  = kB * kT;   // 2048 rows

// ---------------------------------------------------------------- embed ----
__global__ __launch_bounds__(256)
void k_embed(const int* __restrict__ tok, const float* __restrict__ wte,
             const float* __restrict__ wpe, float* __restrict__ x) {
  int idx = blockIdx.x * 256 + threadIdx.x;        // float4 index
  int row = idx / (kD / 4);
  int c4  = idx % (kD / 4);
  int t   = row % kT;
  int token = tok[row];
  float4 a = ((const float4*)wte)[(size_t)token * (kD / 4) + c4];
  float4 b = ((const float4*)wpe)[(size_t)t * (kD / 4) + c4];
  float4 o; o.x = a.x + b.x; o.y = a.y + b.y; o.z = a.z + b.z; o.w = a.w + b.w;
  ((float4*)x)[idx] = o;
}

// ------------------------------------------------------------ layernorm ----
// one wave per row (D=768 = 12 elems/lane), block = 4 waves.
__global__ __launch_bounds__(256)
void k_ln(const float* __restrict__ x, const float* __restrict__ w,
          const float* __restrict__ b, float* __restrict__ out) {
  int wave = threadIdx.x >> 6, lane = threadIdx.x & 63;
  int row = blockIdx.x * 4 + wave;
  const float* xr = x + (size_t)row * kD;
  float v[12];
  float s = 0.f;
#pragma unroll
  for (int i = 0; i < 12; i++) { v[i] = xr[lane + i * 64]; s += v[i]; }
#pragma unroll
  for (int off = 32; off >= 1; off >>= 1) s += __shfl_xor(s, off, 64);
  float mu = s * (1.f / kD);
  float q = 0.f;
#pragma unroll
  for (int i = 0; i < 12; i++) { float d = v[i] - mu; q += d * d; }
#pragma unroll
  for (int off = 32; off >= 1; off >>= 1) q += __shfl_xor(q, off, 64);
  float rs = rsqrtf(q * (1.f / kD) + 1e-5f);
  float* orow = out + (size_t)row * kD;
#pragma unroll
  for (int i = 0; i < 12; i++) {
    int c = lane + i * 64;
    orow[c] = (v[i] - mu) * rs * w[c] + b[c];
  }
}

// ----------------------------------------------------------------- gelu ----
__device__ __forceinline__ float gelu_f(float x) {
  const float c = 0.7978845608028654f;  // sqrt(2/pi)
  float x3 = x * x * x;
  return 0.5f * x * (1.f + tanhf(c * (x + 0.044715f * x3)));
}

// ----------------------------------------------------------------- GEMM ----
// C[M,N] = act(A[M,K] @ W[K,N] + bias) (+ res). BM=BN=64, BK=16,
// 256 threads, 4x4 micro-tile per thread. ACT: 0=none, 1=GELU.
template <int ACT>
__global__ __launch_bounds__(256)
void k_gemm(const float* __restrict__ A, const float* __restrict__ W,
            const float* __restrict__ bias, const float* __restrict__ res,
            float* __restrict__ C, int M, int N, int K) {
  __shared__ float As[16][64];   // As[k][m]
  __shared__ float Ws[16][64];   // Ws[k][n]
  int tid = threadIdx.x;
  int bm = blockIdx.y * 64, bn = blockIdx.x * 64;
  int tx = tid & 15, ty = tid >> 4;          // C tile coords
  int arow = tid >> 2, ak = (tid & 3) * 4;   // A staging
  int wk = tid >> 4, wn = (tid & 15) * 4;    // W staging
  const float* Aptr = A + (size_t)(bm + arow) * K + ak;
  const float* Wptr = W + (size_t)wk * N + bn + wn;
  float acc[4][4] = {};
  for (int k0 = 0; k0 < K; k0 += 16) {
    float4 av = *(const float4*)(Aptr + k0);
    float4 wv = *(const float4*)(Wptr + (size_t)k0 * N);
    __syncthreads();
    As[ak + 0][arow] = av.x; As[ak + 1][arow] = av.y;
    As[ak + 2][arow] = av.z; As[ak + 3][arow] = av.w;
    *(float4*)&Ws[wk][wn] = wv;
    __syncthreads();
#pragma unroll
    for (int kk = 0; kk < 16; kk++) {
      float4 a4 = *(const float4*)&As[kk][ty * 4];
      float4 w4 = *(const float4*)&Ws[kk][tx * 4];
      float am[4] = {a4.x, a4.y, a4.z, a4.w};
      float wm[4] = {w4.x, w4.y, w4.z, w4.w};
#pragma unroll
      for (int i = 0; i < 4; i++)
#pragma unroll
        for (int j = 0; j < 4; j++)
          acc[i][j] = fmaf(am[i], wm[j], acc[i][j]);
    }
  }
  float4 bv = *(const float4*)(bias + bn + tx * 4);
  float bm4[4] = {bv.x, bv.y, bv.z, bv.w};
#pragma unroll
  for (int i = 0; i < 4; i++) {
    int m = bm + ty * 4 + i;
    size_t base = (size_t)m * N + bn + tx * 4;
    float o[4];
#pragma unroll
    for (int j = 0; j < 4; j++) {
      float v = acc[i][j] + bm4[j];
      if (ACT == 1) v = gelu_f(v);
      o[j] = v;
    }
    if (res) {
      float4 rv = *(const float4*)(res + base);
      o[0] += rv.x; o[1] += rv.y; o[2] += rv.z; o[3] += rv.w;
    }
    float4 ov; ov.x = o[0]; ov.y = o[1]; ov.z = o[2]; ov.w = o[3];
    *(float4*)(C + base) = ov;
  }
}

// -------------------------------------------------------- head GEMM (BT) ----
// C[M,N] = A[M,K] @ Wt[N,K]^T  (head_w is stored [V, D] = [N, K]).
__global__ __launch_bounds__(256)
void k_gemm_bt(const float* __restrict__ A, const float* __restrict__ Wt,
               float* __restrict__ C, int M, int N, int K) {
  __shared__ float As[16][64];
  __shared__ float Ws[16][64];
  int tid = threadIdx.x;
  int bm = blockIdx.y * 64, bn = blockIdx.x * 64;
  int tx = tid & 15, ty = tid >> 4;
  int arow = tid >> 2, ak = (tid & 3) * 4;
  int nloc = tid >> 2, nk = (tid & 3) * 4;
  int ng = bn + nloc;
  const float* Aptr = A + (size_t)(bm + arow) * K + ak;
  const float* Wptr = Wt + (size_t)ng * K + nk;
  bool wok = (ng < N);
  float acc[4][4] = {};
  for (int k0 = 0; k0 < K; k0 += 16) {
    float4 av = *(const float4*)(Aptr + k0);
    float4 wv = make_float4(0.f, 0.f, 0.f, 0.f);
    if (wok) wv = *(const float4*)(Wptr + k0);
    __syncthreads();
    As[ak + 0][arow] = av.x; As[ak + 1][arow] = av.y;
    As[ak + 2][arow] = av.z; As[ak + 3][arow] = av.w;
    Ws[nk + 0][nloc] = wv.x; Ws[nk + 1][nloc] = wv.y;
    Ws[nk + 2][nloc] = wv.z; Ws[nk + 3][nloc] = wv.w;
    __syncthreads();
#pragma unroll
    for (int kk = 0; kk < 16; kk++) {
      float4 a4 = *(const float4*)&As[kk][ty * 4];
      float4 w4 = *(const float4*)&Ws[kk][tx * 4];
      float am[4] = {a4.x, a4.y, a4.z, a4.w};
      float wm[4] = {w4.x, w4.y, w4.z, w4.w};
#pragma unroll
      for (int i = 0; i < 4; i++)
#pragma unroll
        for (int j = 0; j < 4; j++)
          acc[i][j] = fmaf(am[i], wm[j], acc[i][j]);
    }
  }
  if (bn + 64 <= N) {
#pragma unroll
    for (int i = 0; i < 4; i++) {
      int m = bm + ty * 4 + i;
      size_t base = (size_t)m * N + bn + tx * 4;
      float4 ov; ov.x = acc[i][0]; ov.y = acc[i][1];
      ov.z = acc[i][2]; ov.w = acc[i][3];
      *(float4*)(C + base) = ov;
    }
  } else {
#pragma unroll
    for (int i = 0; i < 4; i++) {
      int m = bm + ty * 4 + i;
#pragma unroll
      for (int j = 0; j < 4; j++) {
        int n = bn + tx * 4 + j;
        if (n < N) C[(size_t)m * N + n] = acc[i][j];
      }
    }
  }
}

// ------------------------------------------------------------ attention ----
// Flash-style, no materialized scores. Block = 4 waves = 4 consecutive
// queries of one (b,h). Online softmax; K/V chunks of 64 staged in LDS.
__global__ __launch_bounds__(256)
void k_attn(const float* __restrict__ qkv, float* __restrict__ o) {
  __shared__ float Ks[64][65];   // +1 pad: scores phase reads Ks[lane][d]
  __shared__ float Vs[64][65];
  __shared__ float qs[4][64];
  __shared__ float ps[4][64];
  int wave = threadIdx.x >> 6, lane = threadIdx.x & 63;
  int b = blockIdx.z, h = blockIdx.y;
  int q = blockIdx.x * 4 + wave;
  const float* qkv_b = qkv + (size_t)b * kT * (3 * kD);
  qs[wave][lane] = qkv_b[(size_t)q * (3 * kD) + h * kHD + lane];
  float m = -INFINITY, l = 0.f, oacc = 0.f;
  int nch = (blockIdx.x * 4 + 3) / 64 + 1;  // same trip count for all waves
  for (int c = 0; c < nch; c++) {
    __syncthreads();
#pragma unroll
    for (int i = 0; i < 4; i++) {
      int f4 = threadIdx.x + i * 256;           // 0..1023 over 64x16 float4s
      int r = f4 >> 4, c4 = (f4 & 15) * 4;
      const float* kp = qkv_b + (size_t)(c * 64 + r) * (3 * kD) + kD + h * kHD + c4;
      const float* vp = kp + kD;
      float4 kv = *(const float4*)kp;
      float4 vv = *(const float4*)vp;
      Ks[r][c4 + 0] = kv.x; Ks[r][c4 + 1] = kv.y;
      Ks[r][c4 + 2] = kv.z; Ks[r][c4 + 3] = kv.w;
      Vs[r][c4 + 0] = vv.x; Vs[r][c4 + 1] = vv.y;
      Vs[r][c4 + 2] = vv.z; Vs[r][c4 + 3] = vv.w;
    }
    __syncthreads();
    // scores: lane owns key j = lane of this chunk
    float s = 0.f;
#pragma unroll
    for (int d = 0; d < 64; d++) s = fmaf(qs[wave][d], Ks[lane][d], s);
    s *= 0.125f;                                 // 1/sqrt(64)
    int jj = c * 64 + lane;
    if (jj > q) s = -INFINITY;                   // causal mask
    float smax = s;
#pragma unroll
    for (int off = 32; off >= 1; off >>= 1)
      smax = fmaxf(smax, __shfl_xor(smax, off, 64));
    float mnew = fmaxf(m, smax);
    float alpha = expf(m - mnew);                // m=-inf first time -> 0
    float p = expf(s - mnew);                    // masked -> 0
    float psum = p;
#pragma unroll
    for (int off = 32; off >= 1; off >>= 1) psum += __shfl_xor(psum, off, 64);
    l = l * alpha + psum;
    ps[wave][lane] = p;
    __syncthreads();
    // PV: lane owns output dim d = lane
    float pv = 0.f;
#pragma unroll
    for (int j = 0; j < 64; j++) pv = fmaf(ps[wave][j], Vs[j][lane], pv);
    oacc = oacc * alpha + pv;
    m = mnew;
  }
  o[(size_t)(b * kT + q) * kD + h * kHD + lane] = oacc / l;
}

// --------------------------------------------------------------- launch ----
extern "C" void kernel_launch(void* const* d_in, const int* in_sizes, int n_in,
                              void* d_out, int out_size, void* d_ws,
                              size_t ws_size, hipStream_t stream) {
  const int*   tok    = (const int*)d_in[0];
  const float* wte    = (const float*)d_in[1];
  const float* wpe    = (const float*)d_in[2];
  const float* ln1_w  = (const float*)d_in[3];
  const float* ln1_b  = (const float*)d_in[4];
  const float* attn_w = (const float*)d_in[5];
  const float* attn_b = (const float*)d_in[6];
  const float* proj_w = (const float*)d_in[7];
  const float* proj_b = (const float*)d_in[8];
  const float* ln2_w  = (const float*)d_in[9];
  const float* ln2_b  = (const float*)d_in[10];
  const float* fc_w   = (const float*)d_in[11];
  const float* fc_b   = (const float*)d_in[12];
  const float* fc2_w  = (const float*)d_in[13];
  const float* fc2_b  = (const float*)d_in[14];
  const float* lnf_w  = (const float*)d_in[15];
  const float* lnf_b  = (const float*)d_in[16];
  const float* head_w = (const float*)d_in[17];
  float* out = (float*)d_out;

  float* X   = (float*)d_ws;
  float* Hb  = X + (size_t)kM * kD;
  float* QKV = Hb + (size_t)kM * kD;
  float* U   = QKV + (size_t)kM * 3 * kD;

  k_embed<<<(kM * kD / 4) / 256, 256, 0, stream>>>(tok, wte, wpe, X);

  for (int l = 0; l < kL; l++) {
    k_ln<<<kM / 4, 256, 0, stream>>>(X, ln1_w + l * kD, ln1_b + l * kD, Hb);
    k_gemm<0><<<dim3(3 * kD / 64, kM / 64), 256, 0, stream>>>(
        Hb, attn_w + (size_t)l * kD * 3 * kD, attn_b + (size_t)l * 3 * kD,
        nullptr, QKV, kM, 3 * kD, kD);
    k_attn<<<dim3(kT / 4, kH, kB), 256, 0, stream>>>(QKV, Hb);
    k_gemm<0><<<dim3(kD / 64, kM / 64), 256, 0, stream>>>(
        Hb, proj_w + (size_t)l * kD * kD, proj_b + (size_t)l * kD,
        X, X, kM, kD, kD);
    k_ln<<<kM / 4, 256, 0, stream>>>(X, ln2_w + l * kD, ln2_b + l * kD, Hb);
    k_gemm<1><<<dim3(kF / 64, kM / 64), 256, 0, stream>>>(
        Hb, fc_w + (size_t)l * kD * kF, fc_b + (size_t)l * kF,
        nullptr, U, kM, kF, kD);
    k_gemm<0><<<dim3(kD / 64, kM / 64), 256, 0, stream>>>(
        U, fc2_w + (size_t)l * kF * kD, fc2_b + (size_t)l * kD,
        X, X, kM, kD, kF);
  }

  k_ln<<<kM / 4, 256, 0, stream>>>(X, lnf_w, lnf_b, Hb);
  k_gemm_bt<<<dim3((kV + 63) / 64, kM / 64), 256, 0, stream>>>(
      Hb, head_w, out, kM, kV, kD);
}